// Round 4
// baseline (98.595 us; speedup 1.0000x reference)
//
#include <hip/hip_runtime.h>
#include <math.h>

// Problem constants (fixed by the reference)
#define BD   128      // batch == hidden
#define NCOL 1024     // img dim == txt dim
#define NE   32768    // edges
#define CAP  128      // bucket capacity (Poisson lambda=32, max ~60; 128 safe)

// ---------------------------------------------------------------------------
// K1 "prep": three independent task groups co-scheduled in one launch:
//  blocks 0..255  : H precompute
//    HimgT[i,h] = sum_b img[b,i]*W1[h,b] (+ b1[h]);  HtxtT likewise (txt half)
//  blocks 256..511: 32x32 tiled transposes img->imgT, text->textT
//  blocks 512..575: bucket fill via per-block LDS counters (NO global memset,
//    NO global atomics): block owns 32 columns of one side, scans the edge
//    array (int4, L2-hot), LDS-atomicAdd on match, writes cnt[] plain.
// ---------------------------------------------------------------------------
__global__ __launch_bounds__(256) void prep_kernel(
    const float* __restrict__ img, const float* __restrict__ text,
    const int* __restrict__ src, const int* __restrict__ tgt,
    const float* __restrict__ W1, const float* __restrict__ b1,
    float* __restrict__ HimgT, float* __restrict__ HtxtT,
    float* __restrict__ imgT, float* __restrict__ textT,
    int* __restrict__ cnt,
    int* __restrict__ list_src, int* __restrict__ list_tgt)
{
    __shared__ __align__(16) float Wl[64 * 129];  // 33 KB (h) / reused elsewhere
    __shared__ __align__(16) float Sl[128 * 8];   // 4 KB (h) / fill counters
    const int blk = blockIdx.x, tid = threadIdx.x;

    if (blk < 256) {
        // ---- H precompute ----
        const int side = blk >> 7;            // 0: img, 1: txt
        const int i0 = (blk & 127) * 8;
        const float* S = side ? text : img;
        float* Dst = side ? HtxtT : HimgT;
        const int soff = side * 128;

        {   // stage S tile: 128 rows x 8 floats = 256 float4 (coalesced)
            int b = tid >> 1, q = tid & 1;
            ((float4*)Sl)[tid] = *(const float4*)(S + b * 1024 + i0 + q * 4);
        }
        const int h = tid & 127, iq = tid >> 7;
        float acc[4] = {0.f, 0.f, 0.f, 0.f};
        #pragma unroll
        for (int half = 0; half < 2; half++) {
            __syncthreads();
            for (int idx = tid; idx < 8192; idx += 256) {
                int hh = idx >> 6, bb = idx & 63;
                Wl[bb * 129 + hh] = W1[hh * 256 + soff + half * 64 + bb];
            }
            __syncthreads();
            #pragma unroll 8
            for (int bb = 0; bb < 64; bb++) {
                int b = half * 64 + bb;
                float w = Wl[bb * 129 + h];                        // conflict-free
                float4 s4 = *(const float4*)(Sl + b * 8 + iq * 4); // broadcast
                acc[0] += s4.x * w; acc[1] += s4.y * w;
                acc[2] += s4.z * w; acc[3] += s4.w * w;
            }
        }
        float bias = side ? 0.f : b1[h];
        #pragma unroll
        for (int r = 0; r < 4; r++)
            Dst[(i0 + iq * 4 + r) * 128 + h] = acc[r] + bias;
    } else if (blk < 512) {
        // ---- 32x32 tiled transpose (conflict-free via +1 pad) ----
        float (*lds)[33] = (float(*)[33])Wl;     // 32*33 floats of Wl
        const int t = blk - 256;                 // 0..255
        const float* S = (t < 128) ? img : text;
        float* D = (t < 128) ? imgT : textT;
        const int tile = t & 127;                // 4 row-tiles x 32 col-tiles
        const int rt = tile >> 5, ct = tile & 31;
        const int x = tid & 31, y = tid >> 5;    // y 0..7
        #pragma unroll
        for (int k = 0; k < 4; k++) {
            int r = y + k * 8;
            lds[r][x] = S[(rt * 32 + r) * 1024 + ct * 32 + x];
        }
        __syncthreads();
        #pragma unroll
        for (int k = 0; k < 4; k++) {
            int r = y + k * 8;
            D[(ct * 32 + r) * 128 + rt * 32 + x] = lds[x][r];
        }
    } else {
        // ---- bucket fill: 64 blocks, each owns 32 columns of one side ----
        int* lc = (int*)Sl;                      // 32 LDS counters
        const int fb = blk - 512;                // 0..63
        const int side = fb >> 5;                // 0: src buckets, 1: tgt
        const int base = (fb & 31) * 32;         // column range [base, base+32)
        const int* E = side ? tgt : src;
        int* list = side ? list_tgt : list_src;

        if (tid < 32) lc[tid] = 0;
        __syncthreads();

        #pragma unroll 4
        for (int it = 0; it < 32; it++) {        // 32768 edges, int4 per thread
            const int e0 = it * 1024 + tid * 4;
            int4 v = *(const int4*)(E + e0);
            int c;
            c = v.x - base;
            if ((unsigned)c < 32u) { int s = atomicAdd(&lc[c], 1);
                if (s < CAP) list[(base + c) * CAP + s] = e0; }
            c = v.y - base;
            if ((unsigned)c < 32u) { int s = atomicAdd(&lc[c], 1);
                if (s < CAP) list[(base + c) * CAP + s] = e0 + 1; }
            c = v.z - base;
            if ((unsigned)c < 32u) { int s = atomicAdd(&lc[c], 1);
                if (s < CAP) list[(base + c) * CAP + s] = e0 + 2; }
            c = v.w - base;
            if ((unsigned)c < 32u) { int s = atomicAdd(&lc[c], 1);
                if (s < CAP) list[(base + c) * CAP + s] = e0 + 3; }
        }
        __syncthreads();
        if (tid < 32) cnt[side * 1024 + base + tid] = min(lc[tid], CAP);
    }
}

// ---------------------------------------------------------------------------
// K2 "edge": pure MLP, no atomics. 16 lanes per edge, 4 edges per wave,
// ONE pass per wave (2048 blocks x 256 thr = 8192 waves x 4 edges):
//   lane u in [0,16) owns h-elements u*8..u*8+7 (2x float4 from each H row),
//   relu+dot with the matching w2 segment, 4-step shfl_xor reduce in-group.
// ---------------------------------------------------------------------------
__global__ __launch_bounds__(256) void edge_kernel(
    const int* __restrict__ src, const int* __restrict__ tgt,
    const float* __restrict__ HimgT, const float* __restrict__ HtxtT,
    const float* __restrict__ w2, const float* __restrict__ b2,
    float* __restrict__ a_e)
{
    const int lane = threadIdx.x & 63;
    const int u = lane & 15, sub = lane >> 4;               // 4 edges/wave
    const int wid = blockIdx.x * 4 + (threadIdx.x >> 6);    // 0..8191
    const int e = wid * 4 + sub;
    const float4 wa = *(const float4*)(w2 + u * 8);
    const float4 wb = *(const float4*)(w2 + u * 8 + 4);
    const float b2v = b2[0];

    const int s0 = src[e], t0 = tgt[e];
    const float4* Hi = (const float4*)(HimgT + s0 * 128) + u * 2;
    const float4* Ht = (const float4*)(HtxtT + t0 * 128) + u * 2;
    float4 h0 = Hi[0], h1 = Hi[1];
    float4 g0 = Ht[0], g1 = Ht[1];
    float x;
    x  = fmaxf(h0.x + g0.x, 0.f) * wa.x;
    x += fmaxf(h0.y + g0.y, 0.f) * wa.y;
    x += fmaxf(h0.z + g0.z, 0.f) * wa.z;
    x += fmaxf(h0.w + g0.w, 0.f) * wa.w;
    x += fmaxf(h1.x + g1.x, 0.f) * wb.x;
    x += fmaxf(h1.y + g1.y, 0.f) * wb.y;
    x += fmaxf(h1.z + g1.z, 0.f) * wb.z;
    x += fmaxf(h1.w + g1.w, 0.f) * wb.w;
    #pragma unroll
    for (int off = 1; off < 16; off <<= 1)
        x += __shfl_xor(x, off, 64);            // reduce within 16-lane group
    if (u == 0)                                  // lanes 0,16,32,48: e consecutive
        a_e[e] = 1.f / (1.f + expf(-(x + b2v)));
}

// ---------------------------------------------------------------------------
// K3 "gather": atomic-free sparse contraction, one block per (side, column):
//   att_img [b,i] = sum_{e:src=i} a[e]*textT[tgt[e]*128+b]
//   att_text[b,t] = sum_{e:tgt=t} a[e]*imgT[src[e]*128+b]
// Bucket indices/coefs staged in LDS first; then ~32 INDEPENDENT coalesced
// 512 B row reads (L2-hot) feed lane-b FMAs, dual accumulators to break the
// serial chain. Plain store covers every output element -> no output memset.
// ---------------------------------------------------------------------------
__global__ __launch_bounds__(128) void gather_kernel(
    const int* __restrict__ src, const int* __restrict__ tgt,
    const float* __restrict__ a_e,
    const int* __restrict__ cnt,
    const int* __restrict__ list_src, const int* __restrict__ list_tgt,
    const float* __restrict__ imgT, const float* __restrict__ textT,
    float* __restrict__ out)
{
    __shared__ float avl[CAP];
    __shared__ int   ol[CAP];
    const int blk = blockIdx.x, b = threadIdx.x;
    const int side = blk >> 10, c = blk & 1023;
    int n = cnt[side * 1024 + c];               // already clamped to CAP
    const int* lst = (side ? list_tgt : list_src) + c * CAP;
    const int* oth = side ? src : tgt;
    const float* T = side ? imgT : textT;

    if (b < n) {
        int e = lst[b];
        ol[b]  = oth[e];
        avl[b] = a_e[e];
    }
    __syncthreads();

    float acc0 = 0.f, acc1 = 0.f;
    int p = 0;
    for (; p + 1 < n; p += 2) {
        acc0 += avl[p]     * T[ol[p]     * 128 + b];  // LDS broadcast + 512B row
        acc1 += avl[p + 1] * T[ol[p + 1] * 128 + b];
    }
    if (p < n) acc0 += avl[p] * T[ol[p] * 128 + b];

    out[side * (BD * NCOL) + b * 1024 + c] = acc0 + acc1;
}

extern "C" void kernel_launch(void* const* d_in, const int* in_sizes, int n_in,
                              void* d_out, int out_size, void* d_ws, size_t ws_size,
                              hipStream_t stream)
{
    const float* img  = (const float*)d_in[0];   // [128,1024]
    const float* text = (const float*)d_in[1];   // [128,1024]
    const int*   src  = (const int*)  d_in[2];   // [32768]
    const int*   tgt  = (const int*)  d_in[3];   // [32768]
    const float* W1   = (const float*)d_in[4];   // [128,256]
    const float* b1   = (const float*)d_in[5];   // [128]
    const float* w2   = (const float*)d_in[6];   // [128]
    const float* b2   = (const float*)d_in[7];   // [1]
    float* out = (float*)d_out;                  // 2 x [128,1024] concat

    // workspace: ~3.2 MB, no memset needed anywhere
    float* HimgT  = (float*)d_ws;           // 131072 (b1 folded in)
    float* HtxtT  = HimgT + 131072;         // 131072
    float* imgT   = HtxtT + 131072;         // 131072  imgT[i*128+b]
    float* textT  = imgT  + 131072;         // 131072  textT[t*128+b]
    float* a_e    = textT + 131072;         // 32768
    int* cnt      = (int*)(a_e + 32768);    // 2048 (written fully by prep)
    int* list_src = cnt + 2048;             // 1024*CAP
    int* list_tgt = list_src + 1024 * CAP;  // 1024*CAP

    prep_kernel<<<576, 256, 0, stream>>>(img, text, src, tgt, W1, b1,
                                         HimgT, HtxtT, imgT, textT,
                                         cnt, list_src, list_tgt);
    edge_kernel<<<2048, 256, 0, stream>>>(src, tgt, HimgT, HtxtT, w2, b2, a_e);
    gather_kernel<<<2048, 128, 0, stream>>>(src, tgt, a_e, cnt,
                                            list_src, list_tgt,
                                            imgT, textT, out);
}

// Round 5
// 94.330 us; speedup vs baseline: 1.0452x; 1.0452x over previous
//
#include <hip/hip_runtime.h>
#include <math.h>

// Problem constants (fixed by the reference)
#define BD   128      // batch == hidden
#define NCOL 1024     // img dim == txt dim
#define NE   32768    // edges
#define CAP  128      // bucket capacity (Poisson lambda=32, max ~60; 128 safe)
#define CNT_STRIDE 16 // pad counters to 64 B: own cacheline at coherence point

// ---------------------------------------------------------------------------
// K1 "prep": three independent task groups co-scheduled in one launch:
//  blocks 0..255  : H precompute
//    HimgT[i,h] = sum_b img[b,i]*W1[h,b] (+ b1[h]);  HtxtT likewise (txt half)
//  blocks 256..511: 32x32 tiled transposes img->imgT, text->textT
//  blocks 512..639: bucket fill (src/tgt only -> independent of H):
//    slot = atomicAdd(cnt[col]) -> list[col*CAP+slot] = e
//  Atomic latency overlaps with the H-GEMV compute already in flight.
// ---------------------------------------------------------------------------
__global__ __launch_bounds__(256) void prep_kernel(
    const float* __restrict__ img, const float* __restrict__ text,
    const int* __restrict__ src, const int* __restrict__ tgt,
    const float* __restrict__ W1, const float* __restrict__ b1,
    float* __restrict__ HimgT, float* __restrict__ HtxtT,
    float* __restrict__ imgT, float* __restrict__ textT,
    int* __restrict__ cnt,
    int* __restrict__ list_src, int* __restrict__ list_tgt)
{
    __shared__ __align__(16) float Wl[64 * 129];  // 33 KB (h) / reused (transpose)
    __shared__ __align__(16) float Sl[128 * 8];   // 4 KB (h)
    const int blk = blockIdx.x, tid = threadIdx.x;

    if (blk < 256) {
        // ---- H precompute ----
        const int side = blk >> 7;            // 0: img, 1: txt
        const int i0 = (blk & 127) * 8;
        const float* S = side ? text : img;
        float* Dst = side ? HtxtT : HimgT;
        const int soff = side * 128;

        {   // stage S tile: 128 rows x 8 floats = 256 float4 (coalesced)
            int b = tid >> 1, q = tid & 1;
            ((float4*)Sl)[tid] = *(const float4*)(S + b * 1024 + i0 + q * 4);
        }
        const int h = tid & 127, iq = tid >> 7;
        float acc[4] = {0.f, 0.f, 0.f, 0.f};
        #pragma unroll
        for (int half = 0; half < 2; half++) {
            __syncthreads();
            for (int idx = tid; idx < 8192; idx += 256) {
                int hh = idx >> 6, bb = idx & 63;
                Wl[bb * 129 + hh] = W1[hh * 256 + soff + half * 64 + bb];
            }
            __syncthreads();
            #pragma unroll 8
            for (int bb = 0; bb < 64; bb++) {
                int b = half * 64 + bb;
                float w = Wl[bb * 129 + h];                        // conflict-free
                float4 s4 = *(const float4*)(Sl + b * 8 + iq * 4); // broadcast
                acc[0] += s4.x * w; acc[1] += s4.y * w;
                acc[2] += s4.z * w; acc[3] += s4.w * w;
            }
        }
        float bias = side ? 0.f : b1[h];
        #pragma unroll
        for (int r = 0; r < 4; r++)
            Dst[(i0 + iq * 4 + r) * 128 + h] = acc[r] + bias;
    } else if (blk < 512) {
        // ---- 32x32 tiled transpose (conflict-free via +1 pad) ----
        float (*lds)[33] = (float(*)[33])Wl;     // 32*33 floats of Wl
        const int t = blk - 256;                 // 0..255
        const float* S = (t < 128) ? img : text;
        float* D = (t < 128) ? imgT : textT;
        const int tile = t & 127;                // 4 row-tiles x 32 col-tiles
        const int rt = tile >> 5, ct = tile & 31;
        const int x = tid & 31, y = tid >> 5;    // y 0..7
        #pragma unroll
        for (int k = 0; k < 4; k++) {
            int r = y + k * 8;
            lds[r][x] = S[(rt * 32 + r) * 1024 + ct * 32 + x];
        }
        __syncthreads();
        #pragma unroll
        for (int k = 0; k < 4; k++) {
            int r = y + k * 8;
            D[(ct * 32 + r) * 128 + rt * 32 + x] = lds[x][r];
        }
    } else {
        // ---- bucket fill: 128 blocks x 256 thr = 1 edge/thread ----
        const int e = (blk - 512) * 256 + tid;   // 0..32767
        const int s0 = src[e], t0 = tgt[e];
        int p = atomicAdd(&cnt[s0 * CNT_STRIDE], 1);
        if (p < CAP) list_src[s0 * CAP + p] = e;
        int q = atomicAdd(&cnt[(1024 + t0) * CNT_STRIDE], 1);
        if (q < CAP) list_tgt[t0 * CAP + q] = e;
    }
}

// ---------------------------------------------------------------------------
// K2 "edge": pure MLP, no atomics. 16 lanes per edge, 4 edges per wave pass:
//   lane u in [0,16) owns h-elements u*8..u*8+7 (2x float4 from each H row),
//   relu+dot with the matching w2 segment, 4-step shfl_xor reduce in-group.
// 1024 blocks x 256 thr = 4096 waves x 8 edges.
// ---------------------------------------------------------------------------
__global__ __launch_bounds__(256) void edge_kernel(
    const int* __restrict__ src, const int* __restrict__ tgt,
    const float* __restrict__ HimgT, const float* __restrict__ HtxtT,
    const float* __restrict__ w2, const float* __restrict__ b2,
    float* __restrict__ a_e)
{
    const int lane = threadIdx.x & 63;
    const int u = lane & 15, sub = lane >> 4;               // 4 edges/wave pass
    const int wid = blockIdx.x * 4 + (threadIdx.x >> 6);    // 0..4095
    const float4 wa = *(const float4*)(w2 + u * 8);
    const float4 wb = *(const float4*)(w2 + u * 8 + 4);
    const float b2v = b2[0];

    #pragma unroll
    for (int j = 0; j < 2; j++) {
        const int e = wid * 8 + j * 4 + sub;
        const int s0 = src[e], t0 = tgt[e];
        const float4* Hi = (const float4*)(HimgT + s0 * 128) + u * 2;
        const float4* Ht = (const float4*)(HtxtT + t0 * 128) + u * 2;
        float4 h0 = Hi[0], h1 = Hi[1];
        float4 g0 = Ht[0], g1 = Ht[1];
        float x;
        x  = fmaxf(h0.x + g0.x, 0.f) * wa.x;
        x += fmaxf(h0.y + g0.y, 0.f) * wa.y;
        x += fmaxf(h0.z + g0.z, 0.f) * wa.z;
        x += fmaxf(h0.w + g0.w, 0.f) * wa.w;
        x += fmaxf(h1.x + g1.x, 0.f) * wb.x;
        x += fmaxf(h1.y + g1.y, 0.f) * wb.y;
        x += fmaxf(h1.z + g1.z, 0.f) * wb.z;
        x += fmaxf(h1.w + g1.w, 0.f) * wb.w;
        #pragma unroll
        for (int off = 1; off < 16; off <<= 1)
            x += __shfl_xor(x, off, 64);        // reduce within 16-lane group
        if (u == 0)                              // lanes 0,16,32,48: e consecutive
            a_e[e] = 1.f / (1.f + expf(-(x + b2v)));
    }
}

// ---------------------------------------------------------------------------
// K3 "gather": atomic-free sparse contraction, one block per (side, column):
//   att_img [b,i] = sum_{e:src=i} a[e]*textT[tgt[e]*128+b]
//   att_text[b,t] = sum_{e:tgt=t} a[e]*imgT[src[e]*128+b]
// Bucket indices/coefs staged in LDS first; then ~32 INDEPENDENT coalesced
// 512 B row reads (L2-hot) feed lane-b FMAs, dual accumulators to break the
// serial chain. Plain store covers every output element -> no output memset.
// ---------------------------------------------------------------------------
__global__ __launch_bounds__(128) void gather_kernel(
    const int* __restrict__ src, const int* __restrict__ tgt,
    const float* __restrict__ a_e,
    const int* __restrict__ cnt,
    const int* __restrict__ list_src, const int* __restrict__ list_tgt,
    const float* __restrict__ imgT, const float* __restrict__ textT,
    float* __restrict__ out)
{
    __shared__ float avl[CAP];
    __shared__ int   ol[CAP];
    const int blk = blockIdx.x, b = threadIdx.x;
    const int side = blk >> 10, c = blk & 1023;
    int n = cnt[(side * 1024 + c) * CNT_STRIDE];
    n = min(n, CAP);
    const int* lst = (side ? list_tgt : list_src) + c * CAP;
    const int* oth = side ? src : tgt;
    const float* T = side ? imgT : textT;

    if (b < n) {
        int e = lst[b];
        ol[b]  = oth[e];
        avl[b] = a_e[e];
    }
    __syncthreads();

    float acc0 = 0.f, acc1 = 0.f;
    int p = 0;
    for (; p + 1 < n; p += 2) {
        acc0 += avl[p]     * T[ol[p]     * 128 + b];  // LDS broadcast + 512B row
        acc1 += avl[p + 1] * T[ol[p + 1] * 128 + b];
    }
    if (p < n) acc0 += avl[p] * T[ol[p] * 128 + b];

    out[side * (BD * NCOL) + b * 1024 + c] = acc0 + acc1;
}

extern "C" void kernel_launch(void* const* d_in, const int* in_sizes, int n_in,
                              void* d_out, int out_size, void* d_ws, size_t ws_size,
                              hipStream_t stream)
{
    const float* img  = (const float*)d_in[0];   // [128,1024]
    const float* text = (const float*)d_in[1];   // [128,1024]
    const int*   src  = (const int*)  d_in[2];   // [32768]
    const int*   tgt  = (const int*)  d_in[3];   // [32768]
    const float* W1   = (const float*)d_in[4];   // [128,256]
    const float* b1   = (const float*)d_in[5];   // [128]
    const float* w2   = (const float*)d_in[6];   // [128]
    const float* b2   = (const float*)d_in[7];   // [1]
    float* out = (float*)d_out;                  // 2 x [128,1024] concat

    // workspace: ~3.4 MB
    float* HimgT  = (float*)d_ws;           // 131072 (b1 folded in)
    float* HtxtT  = HimgT + 131072;         // 131072
    float* imgT   = HtxtT + 131072;         // 131072  imgT[i*128+b]
    float* textT  = imgT  + 131072;         // 131072  textT[t*128+b]
    float* a_e    = textT + 131072;         // 32768
    int* cnt      = (int*)(a_e + 32768);    // 2048 counters, stride-16 (64 B)
    int* list_src = cnt + 2048 * CNT_STRIDE;// 1024*CAP
    int* list_tgt = list_src + 1024 * CAP;  // 1024*CAP

    hipMemsetAsync(cnt, 0, 2048 * CNT_STRIDE * sizeof(int), stream);
    prep_kernel<<<640, 256, 0, stream>>>(img, text, src, tgt, W1, b1,
                                         HimgT, HtxtT, imgT, textT,
                                         cnt, list_src, list_tgt);
    edge_kernel<<<1024, 256, 0, stream>>>(src, tgt, HimgT, HtxtT, w2, b2, a_e);
    gather_kernel<<<2048, 128, 0, stream>>>(src, tgt, a_e, cnt,
                                            list_src, list_tgt,
                                            imgT, textT, out);
}